// Round 1
// baseline (16130.557 us; speedup 1.0000x reference)
//
#include <hip/hip_runtime.h>
#include <hip/hip_bf16.h>
#include <stdint.h>

typedef unsigned short u16;
typedef unsigned int u32;
typedef __attribute__((ext_vector_type(8))) short s16x8;
typedef __attribute__((ext_vector_type(4))) float f32x4;

#define B_ 32
#define T_ 256
#define L_ 784
#define H_ 512
#define E_ 256
#define V_ 8000

static __device__ __forceinline__ float bf2f(u16 u){
  unsigned v = ((unsigned)u) << 16; return __builtin_bit_cast(float, v);
}
static __device__ __forceinline__ u16 f2bf(float f){
  unsigned u = __builtin_bit_cast(unsigned, f);
  u += 0x7FFFu + ((u >> 16) & 1u);
  return (u16)(u >> 16);
}
static __device__ __forceinline__ float sigm(float x){ return 1.f / (1.f + __expf(-x)); }

typedef __attribute__((address_space(1))) const u32 gu32;
typedef __attribute__((address_space(3))) u32 lu32;
static __device__ __forceinline__ void gload_lds16(const void* g, void* l){
  __builtin_amdgcn_global_load_lds((gu32*)g, (lu32*)l, 16, 0, 0);
}

// ---------------- conversion / prep kernels ----------------

__global__ __launch_bounds__(256) void k_wfull(const float* __restrict__ wih,
                                               const float* __restrict__ whh,
                                               u16* __restrict__ wf){
  int stride = gridDim.x * blockDim.x;
  for (int i = blockIdx.x * blockDim.x + threadIdx.x; i < 2048 * 1280; i += stride){
    int j = i / 1280, k = i - j * 1280;
    float v = (k < 768) ? wih[j * 768 + k] : whh[j * 512 + (k - 768)];
    wf[i] = f2bf(v);
  }
}

__global__ __launch_bounds__(256) void k_whmt(const float* __restrict__ whm,
                                              u16* __restrict__ wt){
  int stride = gridDim.x * blockDim.x;
  for (int i = blockIdx.x * blockDim.x + threadIdx.x; i < 512 * 512; i += stride){
    int n = i >> 9, k = i & 511;
    wt[i] = f2bf(whm[k * 512 + n]);     // transposed: B[n][k] = w_hm[k][n]
  }
}

__global__ __launch_bounds__(256) void k_cvt(const float* __restrict__ s,
                                             u16* __restrict__ d, int n){
  int stride = gridDim.x * blockDim.x * 4;
  for (int i = (blockIdx.x * blockDim.x + threadIdx.x) * 4; i < n; i += stride){
    float4 v = *(const float4*)&s[i];
    d[i + 0] = f2bf(v.x); d[i + 1] = f2bf(v.y);
    d[i + 2] = f2bf(v.z); d[i + 3] = f2bf(v.w);
  }
}

__global__ __launch_bounds__(256) void k_xs(const int* __restrict__ seq,
                                            const float* __restrict__ emb,
                                            u16* __restrict__ xs){
  int stride = gridDim.x * blockDim.x;
  for (int i = blockIdx.x * blockDim.x + threadIdx.x; i < 8192 * 256; i += stride){
    int m = i >> 8, e = i & 255;
    float v = emb[(size_t)seq[m] * 256 + e];
    xs[i] = f2bf(v > 0.f ? v : 0.f);
  }
}

// ---------------- 128x128 bf16 MFMA GEMM: C[M,N] = A[M,K] @ B[N,K]^T ----------------

template<int OUTBF, int HASBIAS, int NG>
__global__ __launch_bounds__(256) void k_gemm(const u16* __restrict__ A,
                                              const u16* __restrict__ Bm,
                                              void* __restrict__ Cout,
                                              const float* __restrict__ bias,
                                              int M, int N, int K){
  __shared__ __align__(16) u16 As[128 * 64];
  __shared__ __align__(16) u16 Bs[128 * 64];
  int tid = threadIdx.x; int w = tid >> 6; int l = tid & 63;
  int m0 = blockIdx.x * 128, n0 = blockIdx.y * 128;
  int wr = w >> 1, wc = w & 1;
  f32x4 acc[4][4];
#pragma unroll
  for (int a = 0; a < 4; a++)
#pragma unroll
    for (int b = 0; b < 4; b++){ f32x4 z = {0.f,0.f,0.f,0.f}; acc[a][b] = z; }

  int rA = m0 + (tid >> 3);
  int rB = n0 + (tid >> 3);
  for (int k0 = 0; k0 < K; k0 += 64){
    __syncthreads();
    int ca = k0 + (tid & 7) * 8;
#pragma unroll
    for (int i = 0; i < 4; i++){
      gload_lds16(&A[(size_t)(rA + i * 32) * K + ca], &As[i * 2048 + w * 512]);
      int rb = rB + i * 32;
      if (NG) rb = (rb < N - 1) ? rb : (N - 1);
      gload_lds16(&Bm[(size_t)rb * K + ca], &Bs[i * 2048 + w * 512]);
    }
    asm volatile("s_waitcnt vmcnt(0)" ::: "memory");
    __syncthreads();
#pragma unroll
    for (int ks = 0; ks < 2; ks++){
      s16x8 av[4], bv[4];
      int ko = ks * 32 + (l >> 4) * 8;
#pragma unroll
      for (int i = 0; i < 4; i++) av[i] = *(const s16x8*)&As[(wr * 64 + i * 16 + (l & 15)) * 64 + ko];
#pragma unroll
      for (int i = 0; i < 4; i++) bv[i] = *(const s16x8*)&Bs[(wc * 64 + i * 16 + (l & 15)) * 64 + ko];
#pragma unroll
      for (int mi = 0; mi < 4; mi++)
#pragma unroll
        for (int ni = 0; ni < 4; ni++)
          acc[mi][ni] = __builtin_amdgcn_mfma_f32_16x16x32_bf16(av[mi], bv[ni], acc[mi][ni], 0, 0, 0);
    }
  }
#pragma unroll
  for (int mi = 0; mi < 4; mi++)
#pragma unroll
    for (int ni = 0; ni < 4; ni++){
      int row = m0 + wr * 64 + mi * 16 + (l >> 4) * 4;
      int col = n0 + wc * 64 + ni * 16 + (l & 15);
      if (NG && col >= N) continue;
#pragma unroll
      for (int r = 0; r < 4; r++){
        float v = acc[mi][ni][r];
        if (HASBIAS) v += bias[col];
        if (OUTBF) ((u16*)Cout)[(size_t)(row + r) * N + col] = f2bf(v);
        else       ((float*)Cout)[(size_t)(row + r) * N + col] = v;
      }
    }
}

// ---------------- per-step: gates + LSTM ----------------
// grid 32 wgs; wg g owns n-slice ns=g*16 across all 4 gates (64 gate-cols).
// A(b,k): k<256 -> xs[b,t,k]; 256<=k<768 -> out_prev; 768<=k<1280 -> h_prev  (Z = [out|h])

__global__ __launch_bounds__(256) void k_gates(const u16* __restrict__ Wf,
                                               const u16* __restrict__ xs,
                                               const u16* __restrict__ Zp,
                                               u16* __restrict__ Zn,
                                               float* __restrict__ cst, int t){
  __shared__ float red[4][32][64];
  int tid = threadIdx.x, w = tid >> 6, l = tid & 63;
  int ns = blockIdx.x * 16;
  f32x4 acc[2][4];
#pragma unroll
  for (int a = 0; a < 2; a++)
#pragma unroll
    for (int b = 0; b < 4; b++){ f32x4 z = {0.f,0.f,0.f,0.f}; acc[a][b] = z; }

  int kbeg = w * 320;
  int kend = kbeg + 320;
  if (t == 0) kend = (kend < 256) ? kend : 256;
  for (int k = kbeg; k < kend; k += 32){
    int ko = k + (l >> 4) * 8;
    s16x8 av[2], bv[4];
#pragma unroll
    for (int mi = 0; mi < 2; mi++){
      int bi = mi * 16 + (l & 15);
      const u16* src = (ko < 256) ? &xs[(size_t)(bi * 256 + t) * 256 + ko]
                                  : &Zp[bi * 1024 + (ko - 256)];
      av[mi] = *(const s16x8*)src;
    }
#pragma unroll
    for (int gi = 0; gi < 4; gi++){
      int j = gi * 512 + ns + (l & 15);
      bv[gi] = *(const s16x8*)&Wf[(size_t)j * 1280 + ko];
    }
#pragma unroll
    for (int mi = 0; mi < 2; mi++)
#pragma unroll
      for (int gi = 0; gi < 4; gi++)
        acc[mi][gi] = __builtin_amdgcn_mfma_f32_16x16x32_bf16(av[mi], bv[gi], acc[mi][gi], 0, 0, 0);
  }
#pragma unroll
  for (int mi = 0; mi < 2; mi++)
#pragma unroll
    for (int gi = 0; gi < 4; gi++)
#pragma unroll
      for (int r = 0; r < 4; r++)
        red[w][mi * 16 + (l >> 4) * 4 + r][gi * 16 + (l & 15)] = acc[mi][gi][r];
  __syncthreads();
  for (int p = tid; p < 512; p += 256){
    int bi = p >> 4, nn = p & 15;
    float iv = 0, fv = 0, gv = 0, ov = 0;
#pragma unroll
    for (int q = 0; q < 4; q++){
      iv += red[q][bi][nn];      fv += red[q][bi][16 + nn];
      gv += red[q][bi][32 + nn]; ov += red[q][bi][48 + nn];
    }
    int n = ns + nn;
    float co = (t == 0) ? 0.f : cst[bi * 512 + n];
    float cn = sigm(fv) * co + sigm(iv) * tanhf(gv);
    float hh = sigm(ov) * tanhf(cn);
    cst[bi * 512 + n] = cn;
    Zn[bi * 1024 + 512 + n] = f2bf(hh);
  }
}

// ---------------- per-step: attention (scores via cnn2, partial softmax, ctx combine) ----------------
// grid 256 = 32 batches x 8 chunks of 98 rows. Last finishing chunk of a batch combines ctx.

__global__ __launch_bounds__(256) void k_attn(const u16* __restrict__ cnn2,
                                              const u16* __restrict__ cnnb,
                                              const u16* __restrict__ Zn,
                                              float* __restrict__ ub,
                                              float* __restrict__ mz,
                                              u32* __restrict__ ready,
                                              u16* __restrict__ ctxb){
  int b = blockIdx.x >> 3, ch = blockIdx.x & 7;
  int l0 = ch * 98;
  int tid = threadIdx.x, w = tid >> 6, ln = tid & 63;
  __shared__ float sc[98];
  __shared__ float sred[4];
  __shared__ u32 oldv;

  float hreg[8];
  {
    s16x8 hv = *(const s16x8*)&Zn[b * 1024 + 512 + ln * 8];
#pragma unroll
    for (int j = 0; j < 8; j++) hreg[j] = bf2f((u16)hv[j]);
  }
  float wmax = -1e30f;
  for (int li = w; li < 98; li += 4){
    s16x8 cv = *(const s16x8*)&cnn2[(size_t)(b * 784 + l0 + li) * 512 + ln * 8];
    float d = 0.f;
#pragma unroll
    for (int j = 0; j < 8; j++) d += hreg[j] * bf2f((u16)cv[j]);
#pragma unroll
    for (int m = 1; m < 64; m <<= 1) d += __shfl_xor(d, m, 64);
    if (ln == 0) sc[li] = d;
    wmax = fmaxf(wmax, d);
  }
  if (ln == 0) sred[w] = wmax;
  __syncthreads();
  float M = fmaxf(fmaxf(sred[0], sred[1]), fmaxf(sred[2], sred[3]));
  __syncthreads();
  float s = 0.f;
  if (tid < 98){ float p = __expf(sc[tid] - M); sc[tid] = p; s = p; }
#pragma unroll
  for (int m = 1; m < 64; m <<= 1) s += __shfl_xor(s, m, 64);
  if (ln == 0) sred[w] = s;
  __syncthreads();
  float S = sred[0] + sred[1] + sred[2] + sred[3];

  float u0 = 0.f, u1 = 0.f;
  int e0 = 2 * tid;
  for (int li = 0; li < 98; li++){
    float p = sc[li];
    u32 pw = *(const u32*)&cnnb[(size_t)(b * 784 + l0 + li) * 512 + e0];
    u0 += p * bf2f((u16)(pw & 0xffff));
    u1 += p * bf2f((u16)(pw >> 16));
  }
  float* up = &ub[(size_t)(b * 8 + ch) * 512];
  up[e0] = u0; up[e0 + 1] = u1;
  if (tid == 0){ mz[(b * 8 + ch) * 2] = M; mz[(b * 8 + ch) * 2 + 1] = S; }
  __threadfence();
  __syncthreads();
  if (tid == 0) oldv = atomicAdd(&ready[b], 1u);
  __syncthreads();
  if (oldv == 7u){
    __threadfence();
    float Mg = -1e30f;
#pragma unroll
    for (int k2 = 0; k2 < 8; k2++) Mg = fmaxf(Mg, mz[(b * 8 + k2) * 2]);
    float Sg = 0.f, al[8];
#pragma unroll
    for (int k2 = 0; k2 < 8; k2++){
      float e = __expf(mz[(b * 8 + k2) * 2] - Mg);
      al[k2] = e;
      Sg += e * mz[(b * 8 + k2) * 2 + 1];
    }
    float c0 = 0.f, c1 = 0.f;
#pragma unroll
    for (int k2 = 0; k2 < 8; k2++){
      float a = al[k2] / Sg;
      const float* uq = &ub[(size_t)(b * 8 + k2) * 512];
      c0 += a * uq[e0]; c1 += a * uq[e0 + 1];
    }
    ctxb[b * 512 + e0] = f2bf(c0);
    ctxb[b * 512 + e0 + 1] = f2bf(c1);
    if (tid == 0) ready[b] = 0;
  }
}

// ---------------- per-step: out = tanh([ctx|h] @ w_out^T) ----------------
// grid 16 wgs x 32 cols; 4 waves K-split 256 each.

__global__ __launch_bounds__(256) void k_out(const u16* __restrict__ wout,
                                             const u16* __restrict__ ctxb,
                                             u16* __restrict__ Zn,
                                             u16* __restrict__ oall, int t){
  __shared__ float red[4][32][32];
  int tid = threadIdx.x, w = tid >> 6, l = tid & 63;
  int ns = blockIdx.x * 32;
  f32x4 acc[2][2];
#pragma unroll
  for (int a = 0; a < 2; a++)
#pragma unroll
    for (int b = 0; b < 2; b++){ f32x4 z = {0.f,0.f,0.f,0.f}; acc[a][b] = z; }
  int kbeg = w * 256;
  for (int k = kbeg; k < kbeg + 256; k += 32){
    int ko = k + (l >> 4) * 8;
    s16x8 av[2], bv[2];
#pragma unroll
    for (int mi = 0; mi < 2; mi++){
      int bi = mi * 16 + (l & 15);
      const u16* src = (ko < 512) ? &ctxb[bi * 512 + ko] : &Zn[bi * 1024 + ko];
      av[mi] = *(const s16x8*)src;
    }
#pragma unroll
    for (int ni = 0; ni < 2; ni++){
      int j = ns + ni * 16 + (l & 15);
      bv[ni] = *(const s16x8*)&wout[(size_t)j * 1024 + ko];
    }
#pragma unroll
    for (int mi = 0; mi < 2; mi++)
#pragma unroll
      for (int ni = 0; ni < 2; ni++)
        acc[mi][ni] = __builtin_amdgcn_mfma_f32_16x16x32_bf16(av[mi], bv[ni], acc[mi][ni], 0, 0, 0);
  }
#pragma unroll
  for (int mi = 0; mi < 2; mi++)
#pragma unroll
    for (int ni = 0; ni < 2; ni++)
#pragma unroll
      for (int r = 0; r < 4; r++)
        red[w][mi * 16 + (l >> 4) * 4 + r][ni * 16 + (l & 15)] = acc[mi][ni][r];
  __syncthreads();
  for (int p = tid; p < 1024; p += 256){
    int bi = p >> 5, nn = p & 31;
    float v = red[0][bi][nn] + red[1][bi][nn] + red[2][bi][nn] + red[3][bi][nn];
    v = tanhf(v);
    u16 hb = f2bf(v);
    int n = ns + nn;
    Zn[bi * 1024 + n] = hb;
    oall[(size_t)(bi * 256 + t) * 512 + n] = hb;
  }
}

// ---------------- log_softmax in place over rows of 8000 ----------------

__global__ __launch_bounds__(256) void k_lsm(float* __restrict__ x){
  size_t base = (size_t)blockIdx.x * 8000;
  int tid = threadIdx.x, w = tid >> 6, ln = tid & 63;
  __shared__ float sred[4];
  float m = -1e30f;
  for (int v = tid; v < 8000; v += 256) m = fmaxf(m, x[base + v]);
#pragma unroll
  for (int mk = 1; mk < 64; mk <<= 1) m = fmaxf(m, __shfl_xor(m, mk, 64));
  if (ln == 0) sred[w] = m;
  __syncthreads();
  float M = fmaxf(fmaxf(sred[0], sred[1]), fmaxf(sred[2], sred[3]));
  __syncthreads();
  float s = 0.f;
  for (int v = tid; v < 8000; v += 256) s += __expf(x[base + v] - M);
#pragma unroll
  for (int mk = 1; mk < 64; mk <<= 1) s += __shfl_xor(s, mk, 64);
  if (ln == 0) sred[w] = s;
  __syncthreads();
  float S = sred[0] + sred[1] + sred[2] + sred[3];
  float lz = M + logf(S);
  for (int v = tid; v < 8000; v += 256) x[base + v] -= lz;
}

// ---------------- launcher ----------------

extern "C" void kernel_launch(void* const* d_in, const int* in_sizes, int n_in,
                              void* d_out, int out_size, void* d_ws, size_t ws_size,
                              hipStream_t stream){
  const float* cnn  = (const float*)d_in[0];
  const int*   seq  = (const int*)d_in[1];
  const float* emb  = (const float*)d_in[2];
  const float* wih  = (const float*)d_in[3];
  const float* whh  = (const float*)d_in[4];
  const float* whm  = (const float*)d_in[5];
  const float* wo   = (const float*)d_in[6];
  const float* wlg  = (const float*)d_in[7];
  const float* blg  = (const float*)d_in[8];

  char* ws = (char*)d_ws;
  u16*   WF     = (u16*)(ws + 0);          // 2048x1280 bf16  (5,242,880 B)
  u16*   WHMT   = (u16*)(ws + 5242880);    // 512x512 bf16 (transposed w_hm)
  u16*   WOUT   = (u16*)(ws + 5767168);    // 512x1024 bf16
  u16*   WLOGIT = (u16*)(ws + 6815744);    // 8000x512 bf16
  u16*   CNNBF  = (u16*)(ws + 15007744);   // 25088x512 bf16
  u16*   CNN2   = (u16*)(ws + 40697856);   // 25088x512 bf16
  u16*   XS     = (u16*)(ws + 66387968);   // 8192x256 bf16
  u16*   OALL   = (u16*)(ws + 70582272);   // 8192x512 bf16
  u16*   ZBUF   = (u16*)(ws + 78970880);   // 2 x 32x1024 bf16
  float* CST    = (float*)(ws + 79101952); // 32x512 f32
  u16*   CTXB   = (u16*)(ws + 79167488);   // 32x512 bf16
  float* UB     = (float*)(ws + 79200256); // 32x8x512 f32
  float* MZ     = (float*)(ws + 79724544); // 32x8x2 f32
  u32*   READY  = (u32*)(ws + 79726592);   // 32 u32

  float* OUT = (float*)d_out;

  hipMemsetAsync(READY, 0, 32 * sizeof(u32), stream);
  k_wfull<<<512, 256, 0, stream>>>(wih, whh, WF);
  k_whmt<<<256, 256, 0, stream>>>(whm, WHMT);
  k_cvt<<<512, 256, 0, stream>>>(wo, WOUT, 512 * 1024);
  k_cvt<<<2048, 256, 0, stream>>>(wlg, WLOGIT, 8000 * 512);
  k_cvt<<<2048, 256, 0, stream>>>(cnn, CNNBF, 25088 * 512);
  k_xs<<<2048, 256, 0, stream>>>(seq, emb, XS);

  {
    dim3 g(196, 4);
    k_gemm<1, 0, 0><<<g, 256, 0, stream>>>(CNNBF, WHMT, CNN2, nullptr, 25088, 512, 512);
  }

  for (int t = 0; t < 256; t++){
    const u16* Zp = ZBUF + (t & 1) * 32768;
    u16*       Zn = ZBUF + ((t + 1) & 1) * 32768;
    k_gates<<<32, 256, 0, stream>>>(WF, XS, Zp, Zn, CST, t);
    k_attn<<<256, 256, 0, stream>>>(CNN2, CNNBF, Zn, UB, MZ, READY, CTXB);
    k_out<<<16, 256, 0, stream>>>(WOUT, CTXB, Zn, OALL, t);
  }

  {
    dim3 g(64, 63);
    k_gemm<0, 1, 1><<<g, 256, 0, stream>>>(OALL, WLOGIT, OUT, blg, 8192, 8000, 512);
  }
  k_lsm<<<8192, 256, 0, stream>>>(OUT);
}